// Round 6
// baseline (14113.954 us; speedup 1.0000x reference)
//
#include <hip/hip_runtime.h>
#include <hip/hip_fp16.h>

#define SEQT 2048
#define HID  256
#define NB   64

typedef _Float16 f16x8 __attribute__((ext_vector_type(8)));
typedef float    f32x4 __attribute__((ext_vector_type(4)));
typedef _Float16 h2    __attribute__((ext_vector_type(2)));

__device__ __forceinline__ float sigf(float x) { return 1.f / (1.f + __expf(-x)); }
__device__ __forceinline__ float tanhf_fast(float x) {
  float e = __expf(-2.f * fabsf(x));
  float r = (1.f - e) / (1.f + e);
  return copysignf(r, x);
}

// One WG (512 thr = 8 waves) per batch element. GEMV gates = Whh*h via MFMA
// 16x16x32_f16 with N=1 batch broadcast to all 16 columns (all cols compute the
// same dot product -> no masking). Wave w owns gate-rows [q*256+32w, +32) for
// q=i,f,g,o. A-fragments (Whh, f16) = 256 dwords/thread live in AGPRs — MFMA
// reads AGPRs natively, eliminating the R2-R5 accvgpr/scratch tax on VALU-read
// weight arrays. h is triple-buffered in LDS in exact B-fragment order (linear
// b128 reads); gates dumped to LDS by lane&15==0 lanes; activations on threads
// 0-255 (one h-unit each). 2 barriers/step. Static 86KB LDS pins the
// compiler's occupancy model at 1 WG/CU (R4-proven AGPR-not-scratch regime).
__global__ __attribute__((amdgpu_flat_work_group_size(512, 512),
                          amdgpu_waves_per_eu(2, 2)))
void lstm_main(
    const float* __restrict__ x, const float* __restrict__ Wih,
    const float* __restrict__ Whh, const float* __restrict__ bih,
    const float* __restrict__ bhh, float* __restrict__ out,
    __half* __restrict__ hist)
{
  __shared__ unsigned int lds[21504];            // 86016 B: forces 1 WG/CU in the model
  float*        gates = (float*)lds;             // [1024] f32
  unsigned int* hbuf  = lds + 1024;              // [3][128] dwords (256 f16 per slot)

  const int t    = threadIdx.x;
  const int b    = blockIdx.x;
  const int w    = t >> 6;                       // wave 0..7
  const int lane = t & 63;
  const int ko   = lane >> 4;                    // k-octet 0..3
  const int lm   = lane & 15;                    // m within 16-tile

  if (t < 384) hbuf[t] = 0u;                     // zero all 3 h slots

  // ---- A-fragments: Whh rows as f16, MFMA layout ----
  // frag (q,st,kt): lane holds A[m = 16*(q*16+2w+st)... i.e. row][k = 32kt+8ko+e]
  f16x8 wv[4][2][8];
#pragma unroll
  for (int q = 0; q < 4; ++q)
#pragma unroll
    for (int st = 0; st < 2; ++st) {
      const float* row = Whh + (size_t)(q * 256 + 32 * w + 16 * st + lm) * HID;
#pragma unroll
      for (int kt = 0; kt < 8; ++kt) {
        const float4* p = (const float4*)(row + 32 * kt + 8 * ko);
        float4 f0 = p[0], f1 = p[1];
        f16x8 v;
        v[0] = (_Float16)f0.x; v[1] = (_Float16)f0.y;
        v[2] = (_Float16)f0.z; v[3] = (_Float16)f0.w;
        v[4] = (_Float16)f1.x; v[5] = (_Float16)f1.y;
        v[6] = (_Float16)f1.z; v[7] = (_Float16)f1.w;
        wv[q][st][kt] = v;
      }
    }

  // per-lane bias + Wih for the 32 (q,st,r) rows this lane accumulates
  float bias[4][2][4], wihv[4][2][4];
#pragma unroll
  for (int q = 0; q < 4; ++q)
#pragma unroll
    for (int st = 0; st < 2; ++st)
#pragma unroll
      for (int r = 0; r < 4; ++r) {
        int row = q * 256 + 32 * w + 16 * st + 4 * ko + r;
        bias[q][st][r] = bih[row] + bhh[row];
        wihv[q][st][r] = Wih[row];
      }
  __syncthreads();

  const float* xb = x + (size_t)b * SEQT;
  __half* hist_b  = hist + (size_t)b * SEQT * HID;
  float c = 0.f, hcur = 0.f;
  float xv = xb[0];
  int wsl = 0, rsl = 2;                          // write slot, read slot (slot 2 zeroed)

  for (int step = 0; step < SEQT; ++step) {
    float xnext = xb[(step + 1) & (SEQT - 1)];   // harmless wrap at last step

    // B-fragments: h(t-1) from LDS, linear conflict-free b128 reads
    const uint4* hp = (const uint4*)(hbuf + rsl * 128);
    f16x8 bf[8];
#pragma unroll
    for (int kt = 0; kt < 8; ++kt)
      bf[kt] = __builtin_bit_cast(f16x8, hp[kt * 4 + ko]);

    // acc init = bias + Wih*x (same for every N-column)
    f32x4 acc[4][2];
#pragma unroll
    for (int q = 0; q < 4; ++q)
#pragma unroll
      for (int st = 0; st < 2; ++st) {
        f32x4 a;
#pragma unroll
        for (int r = 0; r < 4; ++r)
          a[r] = __builtin_fmaf(wihv[q][st][r], xv, bias[q][st][r]);
        acc[q][st] = a;
      }

    // 64 MFMAs: 8 k-tiles x 8 independent accumulator chains
#pragma unroll
    for (int kt = 0; kt < 8; ++kt)
#pragma unroll
      for (int q = 0; q < 4; ++q)
#pragma unroll
        for (int st = 0; st < 2; ++st)
          acc[q][st] = __builtin_amdgcn_mfma_f32_16x16x32_f16(
              wv[q][st][kt], bf[kt], acc[q][st], 0, 0, 0);

    // dump gates (one lane per 16-group; D col 0 == all cols)
    if (lm == 0) {
#pragma unroll
      for (int q = 0; q < 4; ++q)
#pragma unroll
        for (int st = 0; st < 2; ++st)
          *(f32x4*)(gates + q * 256 + 32 * w + 16 * st + 4 * ko) = acc[q][st];
    }
    __syncthreads();

    // activations: thread t<256 owns h-unit j = t
    if (t < 256) {
      float gi = gates[t], gf = gates[256 + t];
      float gg = gates[512 + t], go = gates[768 + t];
      float I = sigf(gi), F = sigf(gf), G = tanhf_fast(gg), O = sigf(go);
      c    = F * c + I * G;
      hcur = O * tanhf_fast(c);
      __half h16 = __float2half(hcur);
      ((__half*)(hbuf + wsl * 128))[t] = h16;    // next step's B-source
      hist_b[(size_t)step * HID + t]   = h16;    // history for linear head
    }
    xv  = xnext;
    rsl = wsl;
    wsl = (wsl == 2) ? 0 : wsl + 1;
    __syncthreads();
  }

  if (t < 256) {
    out[NB * SEQT + b * HID + t]            = hcur;  // h_n
    out[NB * SEQT + NB * HID + b * HID + t] = c;     // c_n
  }
}

// y[b,t] = Wfc . h[b,t,:] + bfc  — one wave per output, coalesced 8B/lane loads.
__global__ __launch_bounds__(256) void lstm_head(
    const __half* __restrict__ hist, const float* __restrict__ Wfc,
    const float* __restrict__ bfc, float* __restrict__ y)
{
  int gw   = (blockIdx.x * 256 + threadIdx.x) >> 6;  // global wave id = output idx
  int lane = threadIdx.x & 63;
  uint2 hv = ((const uint2*)(hist + (size_t)gw * HID))[lane];
  float4 w = ((const float4*)Wfc)[lane];
  h2 p0 = __builtin_bit_cast(h2, hv.x);
  h2 p1 = __builtin_bit_cast(h2, hv.y);
  float s = (float)p0.x * w.x + (float)p0.y * w.y +
            (float)p1.x * w.z + (float)p1.y * w.w;
#pragma unroll
  for (int m = 32; m; m >>= 1) s += __shfl_xor(s, m, 64);
  if (lane == 0) y[gw] = s + bfc[0];
}

extern "C" void kernel_launch(void* const* d_in, const int* in_sizes, int n_in,
                              void* d_out, int out_size, void* d_ws, size_t ws_size,
                              hipStream_t stream)
{
  const float* x   = (const float*)d_in[0];
  const float* Wih = (const float*)d_in[1];
  const float* Whh = (const float*)d_in[2];
  const float* bih = (const float*)d_in[3];
  const float* bhh = (const float*)d_in[4];
  const float* Wfc = (const float*)d_in[5];
  const float* bfc = (const float*)d_in[6];
  float* out      = (float*)d_out;
  __half* hist    = (__half*)d_ws;   // needs 64*2048*256*2 = 64 MiB

  (void)in_sizes; (void)n_in; (void)out_size; (void)ws_size;

  lstm_main<<<dim3(NB), dim3(512), 0, stream>>>(x, Wih, Whh, bih, bhh, out, hist);
  lstm_head<<<dim3((NB * SEQT) / 4), dim3(256), 0, stream>>>(hist, Wfc, bfc, out);
}

// Round 7
// 3600.712 us; speedup vs baseline: 3.9198x; 3.9198x over previous
//
#include <hip/hip_runtime.h>
#include <hip/hip_fp16.h>

#define SEQT 2048
#define HID  256
#define NB   64
#define WSTRIDE 68      // dwords/thread in LDS weight region (64 used + 4 pad; 68%32=4 -> full bank spread)
#define RSLOT   144     // ring slot stride in dwords (4 kg-blocks x 36)
#define KGB     36      // kg-block stride inside a ring slot (32 used + 4; 36%4=0 keeps b128 align, 36%32=4 spreads banks)

typedef _Float16 h2 __attribute__((ext_vector_type(2)));

static __device__ __forceinline__ unsigned pkrtz(float a, float b) {
  return __builtin_bit_cast(unsigned, __builtin_amdgcn_cvt_pkrtz(a, b));  // low=a, high=b
}
static __device__ __forceinline__ float fdot2u(unsigned a, unsigned b, float c) {
  return __builtin_amdgcn_fdot2(__builtin_bit_cast(h2, a),
                                __builtin_bit_cast(h2, b), c, false);
}
static __device__ __forceinline__ float sigf(float x) {
  return __builtin_amdgcn_rcpf(1.f + __expf(-x));
}
static __device__ __forceinline__ float tanhf_fast(float x) {
  float e = __expf(-2.f * fabsf(x));
  float r = (1.f - e) * __builtin_amdgcn_rcpf(1.f + e);
  return copysignf(r, x);
}

// One WG (512 thr) per batch element. k-split decomposition: thread t
// (kg=t&3, rg=t>>2) owns k in [64kg,64kg+64) of the 8 gate rows
// {q*256+2rg, q*256+2rg+1 : q=i,f,g,o}. Partial gates reduced across the
// 4 kg lanes by shfl_xor(1),shfl_xor(2); all 4 replicas compute c/h for
// units 2rg,2rg+1 redundantly (consistent). LDS wave-instrs minimized
// (R2-R6 lesson: step time ~ LDS instr count x ~12cyc):
//   8 b128 h-reads (4-address shared) + 16 b128 weight reads + x/ring ops.
// h ring (16 slots) + x preload -> NO global ops in steady loop (the
// per-step hist store in R1-R4 forced a vmcnt(0) drain at every barrier);
// hist flushed every 16 steps. One barrier/step.
__global__ __attribute__((amdgpu_flat_work_group_size(512, 512),
                          amdgpu_waves_per_eu(2, 2)))
void lstm_main(
    const float* __restrict__ x, const float* __restrict__ Wih,
    const float* __restrict__ Whh, const float* __restrict__ bih,
    const float* __restrict__ bhh, float* __restrict__ out,
    unsigned* __restrict__ hist)   // hist as f16x2 dwords: [b][step][128]
{
  __shared__ unsigned lds[512 * WSTRIDE + 16 * RSLOT + SEQT];
  unsigned* wlds  = lds;                          // [512][WSTRIDE]
  unsigned* hring = lds + 512 * WSTRIDE;          // [16][RSLOT] swizzled
  float*    xs    = (float*)(lds + 512 * WSTRIDE + 16 * RSLOT);  // [2048]

  const int t  = threadIdx.x;
  const int b  = blockIdx.x;
  const int kg = t & 3;
  const int rg = t >> 2;
  const int j0 = 2 * rg, j1 = 2 * rg + 1;
  const int kb = 64 * kg;

  // preload x for this batch (2048 f32, one float4 per thread)
  ((float4*)xs)[t] = ((const float4*)(x + (size_t)b * SEQT))[t];

  // zero ring slot 15 (h before step 0); logical dword u at 36*(u>>5)+(u&31)
  if (t < 128) hring[15 * RSLOT + KGB * (t >> 5) + (t & 31)] = 0u;

  // ---- pack weights ----
  int rows[8];
#pragma unroll
  for (int q = 0; q < 4; ++q) { rows[2 * q] = q * 256 + j0; rows[2 * q + 1] = q * 256 + j1; }

  unsigned wreg[8][24];                           // k-local dwords 0..23
  unsigned* wl = wlds + t * WSTRIDE;              // k-local dwords 24..31 per row
#pragma unroll
  for (int r = 0; r < 8; ++r) {
    const float* wp = Whh + (size_t)rows[r] * HID + kb;
#pragma unroll
    for (int d = 0; d < 24; ++d) wreg[r][d] = pkrtz(wp[2 * d], wp[2 * d + 1]);
#pragma unroll
    for (int d = 0; d < 8; ++d)
      wl[(r >> 1) * 16 + (r & 1) * 8 + d] = pkrtz(wp[48 + 2 * d], wp[49 + 2 * d]);
  }

  unsigned bw[8];                                 // low=bias, high=wih (f16)
#pragma unroll
  for (int r = 0; r < 8; ++r)
    bw[r] = pkrtz(bih[rows[r]] + bhh[rows[r]], Wih[rows[r]]);

  __syncthreads();

  unsigned* histb = hist + (size_t)b * SEQT * 128;
  float c0 = 0.f, c1 = 0.f, h0 = 0.f, h1 = 0.f;
  const _Float16 onef16 = (_Float16)1.f;

  for (int s = 0; s < SEQT; ++s) {
    float xv = xs[s];                             // uniform LDS read
    h2 xp; xp.x = onef16; xp.y = (_Float16)xv;
    unsigned x2 = __builtin_bit_cast(unsigned, xp);

    const uint4* hp = (const uint4*)(hring + ((s + 15) & 15) * RSLOT + KGB * kg);

    float acc[8];
#pragma unroll
    for (int r = 0; r < 8; ++r) {
      float init = fdot2u(bw[r], x2, 0.f);        // bias + wih*x
      acc[r] = (kg == 0) ? init : 0.f;            // bias applied once
    }

    // chunks 0..2: register weights (k-local dwords 0..23)
#pragma unroll
    for (int ch = 0; ch < 3; ++ch) {
      uint4 ha = hp[2 * ch], hb = hp[2 * ch + 1];
      unsigned hd[8] = {ha.x, ha.y, ha.z, ha.w, hb.x, hb.y, hb.z, hb.w};
#pragma unroll
      for (int r = 0; r < 8; ++r)
#pragma unroll
        for (int e = 0; e < 8; ++e)
          acc[r] = fdot2u(wreg[r][8 * ch + e], hd[e], acc[r]);
    }
    // chunk 3: LDS weights (k-local dwords 24..31)
    {
      uint4 ha = hp[6], hb = hp[7];
      unsigned hd[8] = {ha.x, ha.y, ha.z, ha.w, hb.x, hb.y, hb.z, hb.w};
#pragma unroll
      for (int p = 0; p < 4; ++p) {
        uint4 wa = *(const uint4*)(wl + p * 16);
        uint4 wb = *(const uint4*)(wl + p * 16 + 4);
        uint4 wc = *(const uint4*)(wl + p * 16 + 8);
        uint4 wd = *(const uint4*)(wl + p * 16 + 12);
        float a0 = acc[2 * p], a1 = acc[2 * p + 1];
        a0 = fdot2u(wa.x, hd[0], a0); a0 = fdot2u(wa.y, hd[1], a0);
        a0 = fdot2u(wa.z, hd[2], a0); a0 = fdot2u(wa.w, hd[3], a0);
        a0 = fdot2u(wb.x, hd[4], a0); a0 = fdot2u(wb.y, hd[5], a0);
        a0 = fdot2u(wb.z, hd[6], a0); a0 = fdot2u(wb.w, hd[7], a0);
        a1 = fdot2u(wc.x, hd[0], a1); a1 = fdot2u(wc.y, hd[1], a1);
        a1 = fdot2u(wc.z, hd[2], a1); a1 = fdot2u(wc.w, hd[3], a1);
        a1 = fdot2u(wd.x, hd[4], a1); a1 = fdot2u(wd.y, hd[5], a1);
        a1 = fdot2u(wd.z, hd[6], a1); a1 = fdot2u(wd.w, hd[7], a1);
        acc[2 * p] = a0; acc[2 * p + 1] = a1;
      }
    }

    // reduce partials across the 4 kg lanes (lanes differ in bits 0,1)
#pragma unroll
    for (int r = 0; r < 8; ++r) {
      float v = acc[r];
      v += __shfl_xor(v, 1, 64);
      v += __shfl_xor(v, 2, 64);
      acc[r] = v;
    }

    // activations (all 4 replicas compute identically)
    float I0 = sigf(acc[0]), I1 = sigf(acc[1]);
    float F0 = sigf(acc[2]), F1 = sigf(acc[3]);
    float G0 = tanhf_fast(acc[4]), G1 = tanhf_fast(acc[5]);
    float O0 = sigf(acc[6]), O1 = sigf(acc[7]);
    c0 = F0 * c0 + I0 * G0;
    c1 = F1 * c1 + I1 * G1;
    h0 = O0 * tanhf_fast(c0);
    h1 = O1 * tanhf_fast(c1);

    if (kg == 0)
      hring[(s & 15) * RSLOT + KGB * (rg >> 5) + (rg & 31)] = pkrtz(h0, h1);

    if ((s & 15) == 15) {
      __syncthreads();                            // ring fully written
      // flush 16 steps of h (2048 logical dwords) to hist, 1 uint4/thread
      int g  = 4 * t;
      int sl = g >> 7, u = g & 127;
      uint4 v = *(const uint4*)(hring + sl * RSLOT + KGB * (u >> 5) + (u & 31));
      *(uint4*)(histb + (size_t)(s - 15 + sl) * 128 + u) = v;
    }
    __syncthreads();
  }

  if (kg == 0) {
    out[NB * SEQT + b * HID + j0]            = h0;  // h_n
    out[NB * SEQT + b * HID + j1]            = h1;
    out[NB * SEQT + NB * HID + b * HID + j0] = c0;  // c_n
    out[NB * SEQT + NB * HID + b * HID + j1] = c1;
  }
}

// y[b,t] = Wfc . h[b,t,:] + bfc  — one wave per output, coalesced 8B/lane loads.
__global__ __launch_bounds__(256) void lstm_head(
    const unsigned* __restrict__ hist, const float* __restrict__ Wfc,
    const float* __restrict__ bfc, float* __restrict__ y)
{
  int gw   = (blockIdx.x * 256 + threadIdx.x) >> 6;  // global wave id = output idx
  int lane = threadIdx.x & 63;
  uint2 hv = ((const uint2*)(hist + (size_t)gw * 128))[lane];
  float4 w = ((const float4*)Wfc)[lane];
  h2 p0 = __builtin_bit_cast(h2, hv.x);
  h2 p1 = __builtin_bit_cast(h2, hv.y);
  float s = (float)p0.x * w.x + (float)p0.y * w.y +
            (float)p1.x * w.z + (float)p1.y * w.w;
#pragma unroll
  for (int m = 32; m; m >>= 1) s += __shfl_xor(s, m, 64);
  if (lane == 0) y[gw] = s + bfc[0];
}

extern "C" void kernel_launch(void* const* d_in, const int* in_sizes, int n_in,
                              void* d_out, int out_size, void* d_ws, size_t ws_size,
                              hipStream_t stream)
{
  const float* x   = (const float*)d_in[0];
  const float* Wih = (const float*)d_in[1];
  const float* Whh = (const float*)d_in[2];
  const float* bih = (const float*)d_in[3];
  const float* bhh = (const float*)d_in[4];
  const float* Wfc = (const float*)d_in[5];
  const float* bfc = (const float*)d_in[6];
  float* out      = (float*)d_out;
  unsigned* hist  = (unsigned*)d_ws;   // 64*2048*128 dwords = 64 MiB

  (void)in_sizes; (void)n_in; (void)out_size; (void)ws_size;

  lstm_main<<<dim3(NB), dim3(512), 0, stream>>>(x, Wih, Whh, bih, bhh, out, hist);
  lstm_head<<<dim3((NB * SEQT) / 4), dim3(256), 0, stream>>>(hist, Wfc, bfc, out);
}

// Round 8
// 3281.478 us; speedup vs baseline: 4.3011x; 1.0973x over previous
//
#include <hip/hip_runtime.h>
#include <hip/hip_fp16.h>

#define SEQT 2048
#define HID  256
#define NB   64
#define WSTRIDE 68      // dwords/thread in LDS weight region (64 used + 4 pad; stride%32=4 -> bank spread)
#define RSLOT   144     // ring slot stride in dwords (4 kg-blocks x 36)
#define KGB     36      // kg-block stride inside a ring slot

typedef _Float16 h2 __attribute__((ext_vector_type(2)));

static __device__ __forceinline__ unsigned pkrtz(float a, float b) {
  return __builtin_bit_cast(unsigned, __builtin_amdgcn_cvt_pkrtz(a, b));  // low=a, high=b
}
static __device__ __forceinline__ float fdot2u(unsigned a, unsigned b, float c) {
  return __builtin_amdgcn_fdot2(__builtin_bit_cast(h2, a),
                                __builtin_bit_cast(h2, b), c, false);
}
#define LOG2E 1.4426950408889634f
static __device__ __forceinline__ float sigf(float x) {
  // 1/(1+2^(-x*log2e)) — mul, exp2, add, rcp
  return __builtin_amdgcn_rcpf(1.f + __builtin_amdgcn_exp2f(-LOG2E * x));
}
static __device__ __forceinline__ float tanhf_fast(float x) {
  float e = __builtin_amdgcn_exp2f(-2.f * LOG2E * fabsf(x));
  float r = (1.f - e) * __builtin_amdgcn_rcpf(1.f + e);
  return copysignf(r, x);
}
// quad-perm DPP xor-adds: quad = the 4 kg-replicas of one rg (kg = t&3)
static __device__ __forceinline__ float dpp_xadd1(float v) {
  int p = __builtin_amdgcn_update_dpp(0, __builtin_bit_cast(int, v), 0xB1, 0xF, 0xF, true);
  return v + __builtin_bit_cast(float, p);
}
static __device__ __forceinline__ float dpp_xadd2(float v) {
  int p = __builtin_amdgcn_update_dpp(0, __builtin_bit_cast(int, v), 0x4E, 0xF, 0xF, true);
  return v + __builtin_bit_cast(float, p);
}

// One WG (512 thr) per batch element. k-split: thread t (kg=t&3, rg=t>>2) owns
// k in [64kg,64kg+64) of the 8 gate rows {q*256+2rg, q*256+2rg+1}. Partial
// gates reduced across the quad (= 4 kg replicas of rg) with pure-VALU DPP
// quad_perm adds (R7 used ds_swizzle shfl -> LDS pipe, which was co-saturated
// with VALU at ~3000cyc/step). Weights: 24 dw/row in regs (192 dw -> compiler
// splits ~64 arch + 128 AGPR; AGPR reload = minimal 2cyc/dw tax), 8 dw/row in
// LDS. Working set slimmed so total demand fits the 256-reg/wave budget at
// 2 waves/SIMD -> NO scratch (R7's FETCH_SIZE 5.3GB = scratch reloads).
// Bias applied as bias/4 by all 4 replicas (no cndmask). h ring (16 slots) +
// x preload -> no global ops in steady loop; hist flushed every 16 steps.
__global__ __attribute__((amdgpu_flat_work_group_size(512, 512),
                          amdgpu_waves_per_eu(2, 2)))
void lstm_main(
    const float* __restrict__ x, const float* __restrict__ Wih,
    const float* __restrict__ Whh, const float* __restrict__ bih,
    const float* __restrict__ bhh, float* __restrict__ out,
    unsigned* __restrict__ hist)   // hist as f16x2 dwords: [b][step][128]
{
  __shared__ unsigned lds[512 * WSTRIDE + 16 * RSLOT + SEQT];
  unsigned* wlds  = lds;                          // [512][WSTRIDE]
  unsigned* hring = lds + 512 * WSTRIDE;          // [16][RSLOT] swizzled
  float*    xs    = (float*)(lds + 512 * WSTRIDE + 16 * RSLOT);  // [2048]

  const int t  = threadIdx.x;
  const int b  = blockIdx.x;
  const int kg = t & 3;
  const int rg = t >> 2;
  const int j0 = 2 * rg, j1 = 2 * rg + 1;
  const int kb = 64 * kg;

  // preload x for this batch (2048 f32, one float4 per thread)
  ((float4*)xs)[t] = ((const float4*)(x + (size_t)b * SEQT))[t];

  // zero ring slot 15 (h before step 0); logical dword u at KGB*(u>>5)+(u&31)
  if (t < 128) hring[15 * RSLOT + KGB * (t >> 5) + (t & 31)] = 0u;

  // ---- pack weights ----
  unsigned wreg[8][24];                           // k-local dwords 0..23
  unsigned* wl = wlds + t * WSTRIDE;              // k-local dwords 24..31 per row
  unsigned bw[8];                                 // low=bias/4, high=wih/4 (f16)
#pragma unroll
  for (int r = 0; r < 8; ++r) {
    const int row = (r >> 1) * 256 + ((r & 1) ? j1 : j0);   // q=r>>1, unit j0/j1
    const float* wp = Whh + (size_t)row * HID + kb;
#pragma unroll
    for (int d = 0; d < 24; ++d) wreg[r][d] = pkrtz(wp[2 * d], wp[2 * d + 1]);
#pragma unroll
    for (int d = 0; d < 8; ++d)
      wl[(r >> 1) * 16 + (r & 1) * 8 + d] = pkrtz(wp[48 + 2 * d], wp[49 + 2 * d]);
    bw[r] = pkrtz(0.25f * (bih[row] + bhh[row]), 0.25f * Wih[row]);
  }

  __syncthreads();

  unsigned* histb = hist + (size_t)b * SEQT * 128;
  float c0 = 0.f, c1 = 0.f, h0 = 0.f, h1 = 0.f;
  const _Float16 onef16 = (_Float16)1.f;

  for (int s = 0; s < SEQT; ++s) {
    float xv = xs[s];                             // uniform LDS read
    h2 xp; xp.x = onef16; xp.y = (_Float16)xv;
    unsigned x2 = __builtin_bit_cast(unsigned, xp);

    const uint4* hp = (const uint4*)(hring + ((s + 15) & 15) * RSLOT + KGB * kg);

    float acc[8];
#pragma unroll
    for (int r = 0; r < 8; ++r)
      acc[r] = fdot2u(bw[r], x2, 0.f);            // (bias + wih*x)/4, summed x4 by reduce

    // chunks 0..2: register weights (k-local dwords 0..23)
#pragma unroll
    for (int ch = 0; ch < 3; ++ch) {
      uint4 ha = hp[2 * ch], hb = hp[2 * ch + 1];
#pragma unroll
      for (int r = 0; r < 8; ++r) {
        float a = acc[r];
        a = fdot2u(wreg[r][8 * ch + 0], ha.x, a);
        a = fdot2u(wreg[r][8 * ch + 1], ha.y, a);
        a = fdot2u(wreg[r][8 * ch + 2], ha.z, a);
        a = fdot2u(wreg[r][8 * ch + 3], ha.w, a);
        a = fdot2u(wreg[r][8 * ch + 4], hb.x, a);
        a = fdot2u(wreg[r][8 * ch + 5], hb.y, a);
        a = fdot2u(wreg[r][8 * ch + 6], hb.z, a);
        a = fdot2u(wreg[r][8 * ch + 7], hb.w, a);
        acc[r] = a;
      }
    }
    // chunk 3: LDS weights (k-local dwords 24..31)
    {
      uint4 ha = hp[6], hb = hp[7];
#pragma unroll
      for (int p = 0; p < 4; ++p) {
        uint4 wa = *(const uint4*)(wl + p * 16);
        uint4 wb = *(const uint4*)(wl + p * 16 + 4);
        uint4 wc = *(const uint4*)(wl + p * 16 + 8);
        uint4 wd = *(const uint4*)(wl + p * 16 + 12);
        float a0 = acc[2 * p], a1 = acc[2 * p + 1];
        a0 = fdot2u(wa.x, ha.x, a0); a0 = fdot2u(wa.y, ha.y, a0);
        a0 = fdot2u(wa.z, ha.z, a0); a0 = fdot2u(wa.w, ha.w, a0);
        a0 = fdot2u(wb.x, hb.x, a0); a0 = fdot2u(wb.y, hb.y, a0);
        a0 = fdot2u(wb.z, hb.z, a0); a0 = fdot2u(wb.w, hb.w, a0);
        a1 = fdot2u(wc.x, ha.x, a1); a1 = fdot2u(wc.y, ha.y, a1);
        a1 = fdot2u(wc.z, ha.z, a1); a1 = fdot2u(wc.w, ha.w, a1);
        a1 = fdot2u(wd.x, hb.x, a1); a1 = fdot2u(wd.y, hb.y, a1);
        a1 = fdot2u(wd.z, hb.z, a1); a1 = fdot2u(wd.w, hb.w, a1);
        acc[2 * p] = a0; acc[2 * p + 1] = a1;
      }
    }

    // reduce partials across the quad (4 kg replicas) — pure VALU DPP
#pragma unroll
    for (int r = 0; r < 8; ++r) acc[r] = dpp_xadd2(dpp_xadd1(acc[r]));

    // activations (all 4 replicas compute identically)
    float I0 = sigf(acc[0]), I1 = sigf(acc[1]);
    float F0 = sigf(acc[2]), F1 = sigf(acc[3]);
    float G0 = tanhf_fast(acc[4]), G1 = tanhf_fast(acc[5]);
    float O0 = sigf(acc[6]), O1 = sigf(acc[7]);
    c0 = F0 * c0 + I0 * G0;
    c1 = F1 * c1 + I1 * G1;
    h0 = O0 * tanhf_fast(c0);
    h1 = O1 * tanhf_fast(c1);

    if (kg == 0)
      hring[(s & 15) * RSLOT + KGB * (rg >> 5) + (rg & 31)] = pkrtz(h0, h1);

    if ((s & 15) == 15) {
      __syncthreads();                            // ring fully written
      // flush 16 steps of h (2048 logical dwords) to hist, 1 uint4/thread
      int g  = 4 * t;
      int sl = g >> 7, u = g & 127;
      uint4 v = *(const uint4*)(hring + sl * RSLOT + KGB * (u >> 5) + (u & 31));
      *(uint4*)(histb + (size_t)(s - 15 + sl) * 128 + u) = v;
    }
    __syncthreads();
  }

  if (kg == 0) {
    out[NB * SEQT + b * HID + j0]            = h0;  // h_n
    out[NB * SEQT + b * HID + j1]            = h1;
    out[NB * SEQT + NB * HID + b * HID + j0] = c0;  // c_n
    out[NB * SEQT + NB * HID + b * HID + j1] = c1;
  }
}

// y[b,t] = Wfc . h[b,t,:] + bfc  — one wave per output, coalesced 8B/lane loads.
__global__ __launch_bounds__(256) void lstm_head(
    const unsigned* __restrict__ hist, const float* __restrict__ Wfc,
    const float* __restrict__ bfc, float* __restrict__ y)
{
  int gw   = (blockIdx.x * 256 + threadIdx.x) >> 6;  // global wave id = output idx
  int lane = threadIdx.x & 63;
  uint2 hv = ((const uint2*)(hist + (size_t)gw * 128))[lane];
  float4 w = ((const float4*)Wfc)[lane];
  h2 p0 = __builtin_bit_cast(h2, hv.x);
  h2 p1 = __builtin_bit_cast(h2, hv.y);
  float s = (float)p0.x * w.x + (float)p0.y * w.y +
            (float)p1.x * w.z + (float)p1.y * w.w;
#pragma unroll
  for (int m = 32; m; m >>= 1) s += __shfl_xor(s, m, 64);
  if (lane == 0) y[gw] = s + bfc[0];
}

extern "C" void kernel_launch(void* const* d_in, const int* in_sizes, int n_in,
                              void* d_out, int out_size, void* d_ws, size_t ws_size,
                              hipStream_t stream)
{
  const float* x   = (const float*)d_in[0];
  const float* Wih = (const float*)d_in[1];
  const float* Whh = (const float*)d_in[2];
  const float* bih = (const float*)d_in[3];
  const float* bhh = (const float*)d_in[4];
  const float* Wfc = (const float*)d_in[5];
  const float* bfc = (const float*)d_in[6];
  float* out      = (float*)d_out;
  unsigned* hist  = (unsigned*)d_ws;   // 64*2048*128 dwords = 64 MiB

  (void)in_sizes; (void)n_in; (void)out_size; (void)ws_size;

  lstm_main<<<dim3(NB), dim3(512), 0, stream>>>(x, Wih, Whh, bih, bhh, out, hist);
  lstm_head<<<dim3((NB * SEQT) / 4), dim3(256), 0, stream>>>(hist, Wfc, bfc, out);
}

// Round 10
// 3140.164 us; speedup vs baseline: 4.4947x; 1.0450x over previous
//
#include <hip/hip_runtime.h>
#include <hip/hip_fp16.h>

#define SEQT 2048
#define HID  256
#define NB   64
#define WSTRIDE 68      // dwords/thread in LDS weight region (64 used + 4 pad; stride%32=4 -> bank spread)
#define RSLOT   144     // ring slot stride in dwords (4 kg-blocks x 36)
#define KGB     36      // kg-block stride inside a ring slot

typedef _Float16 h2 __attribute__((ext_vector_type(2)));

static __device__ __forceinline__ unsigned pkrtz(float a, float b) {
  return __builtin_bit_cast(unsigned, __builtin_amdgcn_cvt_pkrtz(a, b));  // low=a, high=b
}
static __device__ __forceinline__ float fdot2u(unsigned a, unsigned b, float c) {
  return __builtin_amdgcn_fdot2(__builtin_bit_cast(h2, a),
                                __builtin_bit_cast(h2, b), c, false);
}
#define LOG2E 1.4426950408889634f
static __device__ __forceinline__ float tanhf_fast(float x) {
  float e = __builtin_amdgcn_exp2f(-2.f * LOG2E * fabsf(x));
  float r = (1.f - e) * __builtin_amdgcn_rcpf(1.f + e);
  return copysignf(r, x);
}
// DPP helper: value of v as seen through a quad_perm pattern (ctrl must be
// a compile-time immediate -> template parameter; R9 passed it as a runtime
// arg and failed to compile)
template <int CTRL>
static __device__ __forceinline__ float dppf(float v) {
  int p = __builtin_amdgcn_update_dpp(0, __builtin_bit_cast(int, v), CTRL, 0xF, 0xF, true);
  return __builtin_bit_cast(float, p);
}
#define QP_XOR1 0xB1   // [1,0,3,2]
#define QP_XOR2 0x4E   // [2,3,0,1]
#define QP_BC1  0x55   // [1,1,1,1]
#define QP_30   0x24   // [0,1,2,0]  lane3 <- lane0
#define QP_31   0x64   // [0,1,2,1]  lane3 <- lane1

// One WG (512 thr) per batch element. k-split: thread t (kg=t&3, rg=t>>2) owns
// k in [64kg,64kg+64) of the 8 gate rows {q*256+2rg, q*256+2rg+1}. Partials
// reduced across the quad with DPP xor-adds. R9/R10: activations
// LANE-SPECIALIZED across the quad (R8 computed all 16 transcendentals on all
// 4 replicas): lane kg applies gate-type kg (I/F/G/O) via tanh-unified sigmoid
// (sig(x)=0.5*tanh(x/2)+0.5, per-lane affine consts -> no divergence), then
// c/h assembled with quad_perm DPP ops; lane 3 holds h and writes the ring.
// Transcendentals 16 -> 6 per thread. All else identical to R8.
__global__ __attribute__((amdgpu_flat_work_group_size(512, 512),
                          amdgpu_waves_per_eu(2, 2)))
void lstm_main(
    const float* __restrict__ x, const float* __restrict__ Wih,
    const float* __restrict__ Whh, const float* __restrict__ bih,
    const float* __restrict__ bhh, float* __restrict__ out,
    unsigned* __restrict__ hist)   // hist as f16x2 dwords: [b][step][128]
{
  __shared__ unsigned lds[512 * WSTRIDE + 16 * RSLOT + SEQT];
  unsigned* wlds  = lds;                          // [512][WSTRIDE]
  unsigned* hring = lds + 512 * WSTRIDE;          // [16][RSLOT] swizzled
  float*    xs    = (float*)(lds + 512 * WSTRIDE + 16 * RSLOT);  // [2048]

  const int t  = threadIdx.x;
  const int b  = blockIdx.x;
  const int kg = t & 3;
  const int rg = t >> 2;
  const int j0 = 2 * rg, j1 = 2 * rg + 1;
  const int kb = 64 * kg;

  // per-lane activation constants: lane kg==2 (G gate) -> pure tanh,
  // others -> sigmoid = 0.5*tanh(x/2)+0.5
  const float sc = (kg == 2) ? 1.f : 0.5f;   // pre-scale
  const float am = (kg == 2) ? 1.f : 0.5f;   // affine mul
  const float ab = (kg == 2) ? 0.f : 0.5f;   // affine add

  // preload x for this batch (2048 f32, one float4 per thread)
  ((float4*)xs)[t] = ((const float4*)(x + (size_t)b * SEQT))[t];

  // zero ring slot 15 (h before step 0); logical dword u at KGB*(u>>5)+(u&31)
  if (t < 128) hring[15 * RSLOT + KGB * (t >> 5) + (t & 31)] = 0u;

  // ---- pack weights ----
  unsigned wreg[8][24];                           // k-local dwords 0..23
  unsigned* wl = wlds + t * WSTRIDE;              // k-local dwords 24..31 per row
  unsigned bw[8];                                 // low=bias/4, high=wih/4 (f16)
#pragma unroll
  for (int r = 0; r < 8; ++r) {
    const int row = (r >> 1) * 256 + ((r & 1) ? j1 : j0);   // q=r>>1, unit j0/j1
    const float* wp = Whh + (size_t)row * HID + kb;
#pragma unroll
    for (int d = 0; d < 24; ++d) wreg[r][d] = pkrtz(wp[2 * d], wp[2 * d + 1]);
#pragma unroll
    for (int d = 0; d < 8; ++d)
      wl[(r >> 1) * 16 + (r & 1) * 8 + d] = pkrtz(wp[48 + 2 * d], wp[49 + 2 * d]);
    bw[r] = pkrtz(0.25f * (bih[row] + bhh[row]), 0.25f * Wih[row]);
  }

  __syncthreads();

  unsigned* histb = hist + (size_t)b * SEQT * 128;
  float c0 = 0.f, c1 = 0.f;
  float h0w = 0.f, h1w = 0.f;                     // valid on kg==3 lanes
  const _Float16 onef16 = (_Float16)1.f;

  for (int s = 0; s < SEQT; ++s) {
    float xv = xs[s];                             // uniform LDS read
    h2 xp; xp.x = onef16; xp.y = (_Float16)xv;
    unsigned x2 = __builtin_bit_cast(unsigned, xp);

    const uint4* hp = (const uint4*)(hring + ((s + 15) & 15) * RSLOT + KGB * kg);

    float acc[8];
#pragma unroll
    for (int r = 0; r < 8; ++r)
      acc[r] = fdot2u(bw[r], x2, 0.f);            // (bias + wih*x)/4, summed x4 by reduce

    // chunks 0..2: register weights (k-local dwords 0..23)
#pragma unroll
    for (int ch = 0; ch < 3; ++ch) {
      uint4 ha = hp[2 * ch], hb = hp[2 * ch + 1];
#pragma unroll
      for (int r = 0; r < 8; ++r) {
        float a = acc[r];
        a = fdot2u(wreg[r][8 * ch + 0], ha.x, a);
        a = fdot2u(wreg[r][8 * ch + 1], ha.y, a);
        a = fdot2u(wreg[r][8 * ch + 2], ha.z, a);
        a = fdot2u(wreg[r][8 * ch + 3], ha.w, a);
        a = fdot2u(wreg[r][8 * ch + 4], hb.x, a);
        a = fdot2u(wreg[r][8 * ch + 5], hb.y, a);
        a = fdot2u(wreg[r][8 * ch + 6], hb.z, a);
        a = fdot2u(wreg[r][8 * ch + 7], hb.w, a);
        acc[r] = a;
      }
    }
    // chunk 3: LDS weights (k-local dwords 24..31)
    {
      uint4 ha = hp[6], hb = hp[7];
#pragma unroll
      for (int p = 0; p < 4; ++p) {
        uint4 wa = *(const uint4*)(wl + p * 16);
        uint4 wb = *(const uint4*)(wl + p * 16 + 4);
        uint4 wc = *(const uint4*)(wl + p * 16 + 8);
        uint4 wd = *(const uint4*)(wl + p * 16 + 12);
        float a0 = acc[2 * p], a1 = acc[2 * p + 1];
        a0 = fdot2u(wa.x, ha.x, a0); a0 = fdot2u(wa.y, ha.y, a0);
        a0 = fdot2u(wa.z, ha.z, a0); a0 = fdot2u(wa.w, ha.w, a0);
        a0 = fdot2u(wb.x, hb.x, a0); a0 = fdot2u(wb.y, hb.y, a0);
        a0 = fdot2u(wb.z, hb.z, a0); a0 = fdot2u(wb.w, hb.w, a0);
        a1 = fdot2u(wc.x, ha.x, a1); a1 = fdot2u(wc.y, ha.y, a1);
        a1 = fdot2u(wc.z, ha.z, a1); a1 = fdot2u(wc.w, ha.w, a1);
        a1 = fdot2u(wd.x, hb.x, a1); a1 = fdot2u(wd.y, hb.y, a1);
        a1 = fdot2u(wd.z, hb.z, a1); a1 = fdot2u(wd.w, hb.w, a1);
        acc[2 * p] = a0; acc[2 * p + 1] = a1;
      }
    }

    // reduce partials across the quad (4 kg replicas) — pure VALU DPP
#pragma unroll
    for (int r = 0; r < 8; ++r) {
      float v = acc[r];
      v += dppf<QP_XOR1>(v);
      v += dppf<QP_XOR2>(v);
      acc[r] = v;
    }

    // ---- lane-specialized activations ----
    // lane kg selects gate-type kg for its two units (static cndmask chain)
    float e0 = (kg & 1) ? acc[2] : acc[0];
    float o0 = (kg & 1) ? acc[6] : acc[4];
    float a0 = (kg & 2) ? o0 : e0;                // gate kg, unit 0
    float e1 = (kg & 1) ? acc[3] : acc[1];
    float o1 = (kg & 1) ? acc[7] : acc[5];
    float a1 = (kg & 2) ? o1 : e1;                // gate kg, unit 1

    float g0 = __builtin_fmaf(tanhf_fast(a0 * sc), am, ab);  // L0:I0 L1:F0 L2:G0 L3:O0
    float g1 = __builtin_fmaf(tanhf_fast(a1 * sc), am, ab);

    float P0 = g0 * dppf<QP_XOR2>(g0);            // L0/L2: I0*G0
    float P1 = g1 * dppf<QP_XOR2>(g1);
    float t0 = g0 * c0;                           // L1: F0*c0
    float t1 = g1 * c1;
    float cn0 = t0 + dppf<QP_XOR1>(P0);           // L1: F0*c0 + I0*G0
    float cn1 = t1 + dppf<QP_XOR1>(P1);
    c0 = dppf<QP_BC1>(cn0);                       // broadcast lane1 -> quad
    c1 = dppf<QP_BC1>(cn1);

    float csel = (kg & 1) ? c1 : c0;              // L0:tanh(c0) L1:tanh(c1)
    float th   = tanhf_fast(csel);
    h0w = g0 * dppf<QP_30>(th);                   // L3: O0 * tanh(c0)
    h1w = g1 * dppf<QP_31>(th);                   // L3: O1 * tanh(c1)

    if (kg == 3)
      hring[(s & 15) * RSLOT + KGB * (rg >> 5) + (rg & 31)] = pkrtz(h0w, h1w);

    if ((s & 15) == 15) {
      __syncthreads();                            // ring fully written
      // flush 16 steps of h (2048 logical dwords) to hist, 1 uint4/thread
      int g  = 4 * t;
      int sl = g >> 7, u = g & 127;
      uint4 v = *(const uint4*)(hring + sl * RSLOT + KGB * (u >> 5) + (u & 31));
      *(uint4*)(histb + (size_t)(s - 15 + sl) * 128 + u) = v;
    }
    __syncthreads();
  }

  if (kg == 3) {
    out[NB * SEQT + b * HID + j0]            = h0w;  // h_n
    out[NB * SEQT + b * HID + j1]            = h1w;
    out[NB * SEQT + NB * HID + b * HID + j0] = c0;   // c_n (broadcast-valid)
    out[NB * SEQT + NB * HID + b * HID + j1] = c1;
  }
}

// y[b,t] = Wfc . h[b,t,:] + bfc  — one wave per output, coalesced 8B/lane loads.
__global__ __launch_bounds__(256) void lstm_head(
    const unsigned* __restrict__ hist, const float* __restrict__ Wfc,
    const float* __restrict__ bfc, float* __restrict__ y)
{
  int gw   = (blockIdx.x * 256 + threadIdx.x) >> 6;  // global wave id = output idx
  int lane = threadIdx.x & 63;
  uint2 hv = ((const uint2*)(hist + (size_t)gw * 128))[lane];
  float4 w = ((const float4*)Wfc)[lane];
  h2 p0 = __builtin_bit_cast(h2, hv.x);
  h2 p1 = __builtin_bit_cast(h2, hv.y);
  float s = (float)p0.x * w.x + (float)p0.y * w.y +
            (float)p1.x * w.z + (float)p1.y * w.w;
#pragma unroll
  for (int m = 32; m; m >>= 1) s += __shfl_xor(s, m, 64);
  if (lane == 0) y[gw] = s + bfc[0];
}

extern "C" void kernel_launch(void* const* d_in, const int* in_sizes, int n_in,
                              void* d_out, int out_size, void* d_ws, size_t ws_size,
                              hipStream_t stream)
{
  const float* x   = (const float*)d_in[0];
  const float* Wih = (const float*)d_in[1];
  const float* Whh = (const float*)d_in[2];
  const float* bih = (const float*)d_in[3];
  const float* bhh = (const float*)d_in[4];
  const float* Wfc = (const float*)d_in[5];
  const float* bfc = (const float*)d_in[6];
  float* out      = (float*)d_out;
  unsigned* hist  = (unsigned*)d_ws;   // 64*2048*128 dwords = 64 MiB

  (void)in_sizes; (void)n_in; (void)out_size; (void)ws_size;

  lstm_main<<<dim3(NB), dim3(512), 0, stream>>>(x, Wih, Whh, bih, bhh, out, hist);
  lstm_head<<<dim3((NB * SEQT) / 4), dim3(256), 0, stream>>>(hist, Wfc, bfc, out);
}

// Round 11
// 2001.480 us; speedup vs baseline: 7.0518x; 1.5689x over previous
//
#include <hip/hip_runtime.h>
#include <hip/hip_fp16.h>

#define SEQT 2048
#define HID  256
#define NB   64

typedef int   int32x4 __attribute__((ext_vector_type(4)));
typedef _Float16 h2  __attribute__((ext_vector_type(2)));

#define LOG2E 1.4426950408889634f
static __device__ __forceinline__ float sigf(float x) {
  return __builtin_amdgcn_rcpf(1.f + __builtin_amdgcn_exp2f(-LOG2E * x));
}
static __device__ __forceinline__ float tanhf_fast(float x) {
  float e = __builtin_amdgcn_exp2f(-2.f * LOG2E * fabsf(x));
  float r = (1.f - e) * __builtin_amdgcn_rcpf(1.f + e);
  return copysignf(r, x);
}
static __device__ __forceinline__ float max4(float4 f) {
  return fmaxf(fmaxf(fabsf(f.x), fabsf(f.y)), fmaxf(fabsf(f.z), fabsf(f.w)));
}

// One WG (512 thr = 8 waves) per batch element. Gates = Whh*h on the MATRIX
// pipe: mfma_i32_16x16x64_i8, B = h broadcast to all 16 cols (cols identical).
// Wave w owns gate-rows [128w,128w+128) = 8 row-tiles; 4 k-tiles of K=64.
// A-frags: Whh quantized to i8 (global scale s_w=max|Whh|, computed in-kernel)
// = 128 dw/thread -> fits the 256-unified-reg/wave budget (R6's f16 version
// needed 256 dw and spilled to scratch; that was its ONLY failure). h is
// quantized to i8 at fixed scale 127 (|h|<1) for the MFMA input only; the
// c/h recurrence state stays f32 (error = per-step additive gate noise
// ~1.3e-3). i32 accumulation is exact; gate_f32 = acc*S + bias + wih*x.
// Frag layout identical in structure to R6 (HW-validated): A row=128w+16r+lm,
// k=64kt+16ko+e (bytes little-endian=consecutive k); C/D row=4ko+reg.
// LDS: i8 h-ring (16 slots) + f16 h-ring (flushed to hist every 16 steps,
// linear layout = straight uint4 copy) + gates dump. 2 barriers/step.
__global__ __attribute__((amdgpu_flat_work_group_size(512, 512),
                          amdgpu_waves_per_eu(2, 2)))
void lstm_main(
    const float* __restrict__ x, const float* __restrict__ Wih,
    const float* __restrict__ Whh, const float* __restrict__ bih,
    const float* __restrict__ bhh, float* __restrict__ out,
    unsigned* __restrict__ hist)   // hist as f16x2 dwords: [b][step][128]
{
  __shared__ __align__(16) int           gatesL[1024];
  __shared__ __align__(16) unsigned char qring[16 * 256];   // i8 h ring
  __shared__ __align__(16) unsigned      f16r[16 * 128];    // f16 h ring
  __shared__ float xs[SEQT];
  __shared__ float redf[9];

  const int t    = threadIdx.x;
  const int b    = blockIdx.x;
  const int w    = t >> 6;
  const int lane = t & 63;
  const int ko   = lane >> 4;       // k-sixteen group 0..3
  const int lm   = lane & 15;       // row within 16-tile

  // preload x for this batch
  ((float4*)xs)[t] = ((const float4*)(x + (size_t)b * SEQT))[t];
  // zero i8 ring slot 15 (h before step 0)
  if (t < 64) ((unsigned*)qring)[15 * 64 + t] = 0u;

  // ---- pass 1: global max |Whh| (the WG's 8 waves cover all 1024 rows) ----
  float mx = 0.f;
#pragma unroll
  for (int r = 0; r < 8; ++r) {
    const float* rp = Whh + (size_t)(128 * w + 16 * r + lm) * HID + 16 * ko;
#pragma unroll
    for (int kt = 0; kt < 4; ++kt) {
      const float4* p = (const float4*)(rp + 64 * kt);
      mx = fmaxf(mx, fmaxf(fmaxf(max4(p[0]), max4(p[1])),
                           fmaxf(max4(p[2]), max4(p[3]))));
    }
  }
#pragma unroll
  for (int o = 32; o; o >>= 1) mx = fmaxf(mx, __shfl_xor(mx, o, 64));
  if (lane == 0) redf[w] = mx;
  __syncthreads();
  if (t == 0) {
    float m = redf[0];
#pragma unroll
    for (int i = 1; i < 8; ++i) m = fmaxf(m, redf[i]);
    redf[8] = m;
  }
  __syncthreads();
  const float s_w  = redf[8];
  const float winv = 127.f / s_w;
  const float S    = s_w / (127.f * 127.f);      // acc_i32 -> f32 gate scale

  // ---- pass 2: load + quantize A-fragments (128 dwords/thread) ----
  int32x4 af[8][4];
#pragma unroll
  for (int r = 0; r < 8; ++r) {
    const float* rp = Whh + (size_t)(128 * w + 16 * r + lm) * HID + 16 * ko;
#pragma unroll
    for (int kt = 0; kt < 4; ++kt) {
      const float4* p = (const float4*)(rp + 64 * kt);
      int32x4 v;
#pragma unroll
      for (int d = 0; d < 4; ++d) {
        float4 f = p[d];
        int q0 = (int)__builtin_rintf(f.x * winv);
        int q1 = (int)__builtin_rintf(f.y * winv);
        int q2 = (int)__builtin_rintf(f.z * winv);
        int q3 = (int)__builtin_rintf(f.w * winv);
        v[d] = (q0 & 255) | ((q1 & 255) << 8) | ((q2 & 255) << 16) | ((q3 & 255) << 24);
      }
      af[r][kt] = v;
    }
  }

  // act-thread constants: unit u = t (<256) needs rows {u,256+u,512+u,768+u}
  float b4[4] = {0, 0, 0, 0}, w4[4] = {0, 0, 0, 0};
  if (t < 256) {
#pragma unroll
    for (int q = 0; q < 4; ++q) {
      int row = q * 256 + t;
      b4[q] = bih[row] + bhh[row];
      w4[q] = Wih[row];
    }
  }
  __syncthreads();

  unsigned* histb = hist + (size_t)b * SEQT * 128;
  float c = 0.f, h = 0.f;
  const int32x4 z4 = {0, 0, 0, 0};

  for (int s = 0; s < SEQT; ++s) {
    // ---- MFMA phase: gates_i32 = Whh_i8 * h_i8 ----
    const unsigned char* qs = qring + ((s + 15) & 15) * 256;
    int32x4 bf0 = *(const int32x4*)(qs + 16 * ko);
    int32x4 bf1 = *(const int32x4*)(qs + 64 + 16 * ko);
    int32x4 bf2 = *(const int32x4*)(qs + 128 + 16 * ko);
    int32x4 bf3 = *(const int32x4*)(qs + 192 + 16 * ko);
#pragma unroll
    for (int r = 0; r < 8; ++r) {
      int32x4 a = __builtin_amdgcn_mfma_i32_16x16x64_i8(af[r][0], bf0, z4, 0, 0, 0);
      a = __builtin_amdgcn_mfma_i32_16x16x64_i8(af[r][1], bf1, a, 0, 0, 0);
      a = __builtin_amdgcn_mfma_i32_16x16x64_i8(af[r][2], bf2, a, 0, 0, 0);
      a = __builtin_amdgcn_mfma_i32_16x16x64_i8(af[r][3], bf3, a, 0, 0, 0);
      if (lm == 0) *(int32x4*)(gatesL + 128 * w + 16 * r + 4 * ko) = a;
    }
    __syncthreads();

    // ---- activation phase: threads 0..255, unit u = t ----
    if (t < 256) {
      float xv = xs[s];
      float a0 = __builtin_fmaf((float)gatesL[t],       S, __builtin_fmaf(w4[0], xv, b4[0]));
      float a1 = __builtin_fmaf((float)gatesL[256 + t], S, __builtin_fmaf(w4[1], xv, b4[1]));
      float a2 = __builtin_fmaf((float)gatesL[512 + t], S, __builtin_fmaf(w4[2], xv, b4[2]));
      float a3 = __builtin_fmaf((float)gatesL[768 + t], S, __builtin_fmaf(w4[3], xv, b4[3]));
      float I = sigf(a0), F = sigf(a1), G = tanhf_fast(a2), O = sigf(a3);
      c = F * c + I * G;
      h = O * tanhf_fast(c);
      ((_Float16*)f16r)[(s & 15) * 256 + t] = (_Float16)h;   // f16 ring (hist/head)
      int q = (int)__builtin_rintf(h * 127.f);
      ((char*)qring)[(s & 15) * 256 + t] = (char)q;          // i8 ring (next B)
    }
    __syncthreads();

    // ---- flush f16 ring -> hist every 16 steps (linear layout: plain copy) ----
    if ((s & 15) == 15) {
      uint4 v = *(const uint4*)(f16r + 4 * t);
      *(uint4*)(histb + (size_t)(s - 15) * 128 + 4 * t) = v;
    }
  }

  if (t < 256) {
    out[NB * SEQT + b * HID + t]            = h;   // h_n
    out[NB * SEQT + NB * HID + b * HID + t] = c;   // c_n
  }
}

// y[b,t] = Wfc . h[b,t,:] + bfc  — one wave per output, coalesced 8B/lane loads.
__global__ __launch_bounds__(256) void lstm_head(
    const unsigned* __restrict__ hist, const float* __restrict__ Wfc,
    const float* __restrict__ bfc, float* __restrict__ y)
{
  int gw   = (blockIdx.x * 256 + threadIdx.x) >> 6;  // global wave id = output idx
  int lane = threadIdx.x & 63;
  uint2 hv = ((const uint2*)(hist + (size_t)gw * 128))[lane];
  float4 w = ((const float4*)Wfc)[lane];
  h2 p0 = __builtin_bit_cast(h2, hv.x);
  h2 p1 = __builtin_bit_cast(h2, hv.y);
  float s = (float)p0.x * w.x + (float)p0.y * w.y +
            (float)p1.x * w.z + (float)p1.y * w.w;
#pragma unroll
  for (int m = 32; m; m >>= 1) s += __shfl_xor(s, m, 64);
  if (lane == 0) y[gw] = s + bfc[0];
}

extern "C" void kernel_launch(void* const* d_in, const int* in_sizes, int n_in,
                              void* d_out, int out_size, void* d_ws, size_t ws_size,
                              hipStream_t stream)
{
  const float* x   = (const float*)d_in[0];
  const float* Wih = (const float*)d_in[1];
  const float* Whh = (const float*)d_in[2];
  const float* bih = (const float*)d_in[3];
  const float* bhh = (const float*)d_in[4];
  const float* Wfc = (const float*)d_in[5];
  const float* bfc = (const float*)d_in[6];
  float* out      = (float*)d_out;
  unsigned* hist  = (unsigned*)d_ws;   // 64*2048*128 dwords = 64 MiB

  (void)in_sizes; (void)n_in; (void)out_size; (void)ws_size;

  lstm_main<<<dim3(NB), dim3(512), 0, stream>>>(x, Wih, Whh, bih, bhh, out, hist);
  lstm_head<<<dim3((NB * SEQT) / 4), dim3(256), 0, stream>>>(hist, Wfc, bfc, out);
}

// Round 12
// 1643.312 us; speedup vs baseline: 8.5887x; 1.2180x over previous
//
#include <hip/hip_runtime.h>
#include <hip/hip_fp16.h>

#define SEQT 2048
#define HID  256
#define NB   64

typedef int int32x4 __attribute__((ext_vector_type(4)));
typedef _Float16 h2 __attribute__((ext_vector_type(2)));

#define LOG2E 1.4426950408889634f
static __device__ __forceinline__ float sigf(float x) {
  return __builtin_amdgcn_rcpf(1.f + __builtin_amdgcn_exp2f(-LOG2E * x));
}
static __device__ __forceinline__ float tanhf_fast(float x) {
  float e = __builtin_amdgcn_exp2f(-2.f * LOG2E * fabsf(x));
  float r = (1.f - e) * __builtin_amdgcn_rcpf(1.f + e);
  return copysignf(r, x);
}
static __device__ __forceinline__ float max4(float4 f) {
  return fmaxf(fmaxf(fabsf(f.x), fabsf(f.y)), fmaxf(fabsf(f.z), fabsf(f.w)));
}

// One WG (512 thr = 8 waves) per batch. Gates = Whh*h via mfma_i32_16x16x64_i8
// (B = h broadcast to 16 cols). R12 remap: wave w owns ALL FOUR gates of units
// [32w,32w+32): tile r=(q,s) = rows q*256+32w+16s (8 tiles x 4 k-tiles = 32
// MFMA/wave/step, the A-coverage floor). D-layout (verified by R11's pass):
// lane (ko,lm) reg j holds row 4ko+j of each tile, all cols equal -> the SAME
// lane holds I,F,G,O of unit u = 32w+16su+4ko+ru (su,ru from lm, static).
// Activations therefore run IN-REGISTER right after the MFMA chain: static
// cndmask select tree (7 ops/gate), no gates-LDS round trip, no act phase,
// ONE barrier/step (R11 had 2 + a full LDS exchange). Per-row weight scales
// (rowmax via ko-shfl reduce; S published once via LDS). i8 h-ring (16 slots)
// + f16 h-ring flushed to hist every 16 steps (extra barrier only then).
__global__ __attribute__((amdgpu_flat_work_group_size(512, 512),
                          amdgpu_waves_per_eu(2, 2)))
void lstm_main(const float* __restrict__ x, const float* __restrict__ Wih,
               const float* __restrict__ Whh, const float* __restrict__ bih,
               const float* __restrict__ bhh, float* __restrict__ out,
               unsigned* __restrict__ hist)   // hist f16x2 dwords: [b][step][128]
{
  __shared__ __align__(16) unsigned char qring[16 * 256];   // i8 h ring
  __shared__ __align__(16) unsigned      f16r[16 * 128];    // f16 h ring
  __shared__ float xs[SEQT];
  __shared__ float rowS[1024];                               // per-row gate scale

  const int t    = threadIdx.x;
  const int b    = blockIdx.x;
  const int w    = t >> 6;
  const int lane = t & 63;
  const int ko   = lane >> 4;       // k-16-group / D-row-quad 0..3
  const int lm   = lane & 15;       // A-row within tile / D-col
  const int su   = (lm >> 2) & 1;   // tile-half this lane activates
  const int ru   = lm & 3;          // reg this lane activates
  const int u    = 32 * w + 16 * su + 4 * ko + ru;   // unit (dup for lm>=8)

  ((float4*)xs)[t] = ((const float4*)(x + (size_t)b * SEQT))[t];
  if (t < 64) ((unsigned*)qring)[15 * 64 + t] = 0u;   // zero slot 15 (h pre-step0)

  // ---- per-row max + quantize A-fragments (128 dw/thread -> AGPR) ----
  int32x4 af[8][4];
#pragma unroll
  for (int r = 0; r < 8; ++r) {
    const int q = r >> 1, sh = r & 1;
    const int row = q * 256 + 32 * w + 16 * sh + lm;
    const float* rp = Whh + (size_t)row * HID + 16 * ko;
    float mx = 1e-20f;
#pragma unroll
    for (int kt = 0; kt < 4; ++kt) {
      const float4* p = (const float4*)(rp + 64 * kt);
      mx = fmaxf(mx, fmaxf(fmaxf(max4(p[0]), max4(p[1])),
                           fmaxf(max4(p[2]), max4(p[3]))));
    }
    mx = fmaxf(mx, __shfl_xor(mx, 16, 64));   // reduce across ko groups
    mx = fmaxf(mx, __shfl_xor(mx, 32, 64));   // (lanes differ in bits 4,5)
    const float winv = 127.f / mx;
    if (ko == 0) rowS[row] = mx * (1.f / (127.f * 127.f));
#pragma unroll
    for (int kt = 0; kt < 4; ++kt) {
      const float4* p = (const float4*)(rp + 64 * kt);
      int32x4 v;
#pragma unroll
      for (int d = 0; d < 4; ++d) {
        float4 f = p[d];
        int q0 = (int)__builtin_rintf(f.x * winv);
        int q1 = (int)__builtin_rintf(f.y * winv);
        int q2 = (int)__builtin_rintf(f.z * winv);
        int q3 = (int)__builtin_rintf(f.w * winv);
        v[d] = (q0 & 255) | ((q1 & 255) << 8) | ((q2 & 255) << 16) | ((q3 & 255) << 24);
      }
      af[r][kt] = v;
    }
  }

  // per-lane act constants for unit u: rows q*256+u
  float biasu[4], wihu[4];
#pragma unroll
  for (int q = 0; q < 4; ++q) {
    int row = q * 256 + u;
    biasu[q] = bih[row] + bhh[row];
    wihu[q]  = Wih[row];
  }
  __syncthreads();
  float Su[4];
#pragma unroll
  for (int q = 0; q < 4; ++q) Su[q] = rowS[q * 256 + u];

  unsigned* histb = hist + (size_t)b * SEQT * 128;
  float c = 0.f, h = 0.f;
  const int32x4 z4 = {0, 0, 0, 0};

  for (int s = 0; s < SEQT; ++s) {
    float xv = xs[s];
    const unsigned char* qs = qring + ((s + 15) & 15) * 256;
    int32x4 bf[4];
#pragma unroll
    for (int kt = 0; kt < 4; ++kt)
      bf[kt] = *(const int32x4*)(qs + 64 * kt + 16 * ko);   // broadcast b128

    // 32 MFMA: 8 independent 4-deep chains, interleaved for issue
    int32x4 acc[8];
#pragma unroll
    for (int r = 0; r < 8; ++r)
      acc[r] = __builtin_amdgcn_mfma_i32_16x16x64_i8(af[r][0], bf[0], z4, 0, 0, 0);
#pragma unroll
    for (int kt = 1; kt < 4; ++kt)
#pragma unroll
      for (int r = 0; r < 8; ++r)
        acc[r] = __builtin_amdgcn_mfma_i32_16x16x64_i8(af[r][kt], bf[kt], acc[r], 0, 0, 0);

    // static select: gate q of unit u = acc[2q+su][ru]
    float aq[4];
#pragma unroll
    for (int q = 0; q < 4; ++q) {
      int32x4 v0 = acc[2 * q], v1 = acc[2 * q + 1];
      int e0 = su ? v1[0] : v0[0];
      int e1 = su ? v1[1] : v0[1];
      int e2 = su ? v1[2] : v0[2];
      int e3 = su ? v1[3] : v0[3];
      int g01 = (ru & 1) ? e1 : e0;
      int g23 = (ru & 1) ? e3 : e2;
      int gv  = (ru & 2) ? g23 : g01;
      aq[q] = __builtin_fmaf((float)gv, Su[q],
                             __builtin_fmaf(wihu[q], xv, biasu[q]));
    }

    float I = sigf(aq[0]), F = sigf(aq[1]), G = tanhf_fast(aq[2]), O = sigf(aq[3]);
    c = F * c + I * G;
    h = O * tanhf_fast(c);

    if (lm < 8) {                                  // one writer per unit
      int qv = (int)__builtin_rintf(h * 127.f);
      ((char*)qring)[(s & 15) * 256 + u]      = (char)qv;       // next B-source
      ((_Float16*)f16r)[(s & 15) * 256 + u]   = (_Float16)h;    // hist ring
    }
    __syncthreads();                               // h ring ready for step s+1

    if ((s & 15) == 15) {                          // flush 16 steps of h
      uint4 v = *(const uint4*)(f16r + 4 * t);
      *(uint4*)(histb + (size_t)(s - 15) * 128 + 4 * t) = v;
      __syncthreads();                             // protect ring vs next writes
    }
  }

  if (lm < 8) {
    out[NB * SEQT + b * HID + u]            = h;   // h_n
    out[NB * SEQT + NB * HID + b * HID + u] = c;   // c_n
  }
}

// y[b,t] = Wfc . h[b,t,:] + bfc  — one wave per output, coalesced 8B/lane loads.
__global__ __launch_bounds__(256) void lstm_head(
    const unsigned* __restrict__ hist, const float* __restrict__ Wfc,
    const float* __restrict__ bfc, float* __restrict__ y)
{
  int gw   = (blockIdx.x * 256 + threadIdx.x) >> 6;  // global wave id = output idx
  int lane = threadIdx.x & 63;
  uint2 hv = ((const uint2*)(hist + (size_t)gw * 128))[lane];
  float4 w = ((const float4*)Wfc)[lane];
  h2 p0 = __builtin_bit_cast(h2, hv.x);
  h2 p1 = __builtin_bit_cast(h2, hv.y);
  float s = (float)p0.x * w.x + (float)p0.y * w.y +
            (float)p1.x * w.z + (float)p1.y * w.w;
#pragma unroll
  for (int m = 32; m; m >>= 1) s += __shfl_xor(s, m, 64);
  if (lane == 0) y[gw] = s + bfc[0];
}

extern "C" void kernel_launch(void* const* d_in, const int* in_sizes, int n_in,
                              void* d_out, int out_size, void* d_ws, size_t ws_size,
                              hipStream_t stream)
{
  const float* x   = (const float*)d_in[0];
  const float* Wih = (const float*)d_in[1];
  const float* Whh = (const float*)d_in[2];
  const float* bih = (const float*)d_in[3];
  const float* bhh = (const float*)d_in[4];
  const float* Wfc = (const float*)d_in[5];
  const float* bfc = (const float*)d_in[6];
  float* out      = (float*)d_out;
  unsigned* hist  = (unsigned*)d_ws;   // 64*2048*128 dwords = 64 MiB

  (void)in_sizes; (void)n_in; (void)out_size; (void)ws_size;

  lstm_main<<<dim3(NB), dim3(512), 0, stream>>>(x, Wih, Whh, bih, bhh, out, hist);
  lstm_head<<<dim3((NB * SEQT) / 4), dim3(256), 0, stream>>>(hist, Wfc, bfc, out);
}